// Round 11
// baseline (317.267 us; speedup 1.0000x reference)
//
#include <hip/hip_runtime.h>
#include <hip/hip_fp16.h>
#include <math.h>

#define NEG_SLOPE 0.2f
#define GAT_EPS 1e-16f

#define CH   8192   // edges per chunk (k_cnt / k_place)
#define NBK  256    // coarse buckets; bucket = d >> SHIFT (512 nodes/bucket)
// Pack constraint: s < 2^17 (N <= 131072) and (d & 511) in bits 17..25.

// ---- bf16 pair packing helpers (channel 2p in low half, 2p+1 in high) ----
__device__ __forceinline__ unsigned pack_bf16(float a, float b) {
    unsigned ua = __float_as_uint(a);
    unsigned ub = __float_as_uint(b);
    ua = (ua + 0x8000u) >> 16;
    ub = (ub + 0x8000u) & 0xffff0000u;
    return ua | ub;
}
__device__ __forceinline__ float bf_lo(unsigned pk) {
    return __uint_as_float(pk << 16);
}
__device__ __forceinline__ float bf_hi(unsigned pk) {
    return __uint_as_float(pk & 0xffff0000u);
}

// ===========================================================================
// CSR build via deterministic two-level counting sort — ZERO global atomics.
// Edge ids e >= E are self-loops (s = d = e - E). ei[0..E)=src, ei[E..2E)=dst.
// ===========================================================================

// Pass A: per-chunk LDS histogram over coarse buckets -> cnt[chunk][NBK].
__global__ __launch_bounds__(256) void k_cnt(
    const int* __restrict__ ei, int E, int N, int shift,
    int* __restrict__ cnt)
{
    __shared__ int h[NBK];
    int c = blockIdx.x;
    h[threadIdx.x] = 0;
    __syncthreads();
    int Etot = E + N;
    int base = c * CH;
    int lim = min(base + CH, Etot);
    for (int e = base + threadIdx.x; e < lim; e += 256) {
        int d = (e < E) ? ei[E + e] : (e - E);
        atomicAdd(&h[d >> shift], 1);
    }
    __syncthreads();
    cnt[c * NBK + threadIdx.x] = h[threadIdx.x];
}

// Pass B1: PARALLEL per-bucket scan over chunks (block = bucket).
__global__ __launch_bounds__(256) void k_off_a(
    const int* __restrict__ cnt, int* __restrict__ off,
    int* __restrict__ tot, int NCH)
{
    __shared__ int sm[256];
    int b = blockIdx.x;
    int t = threadIdx.x;
    int carry = 0;
    for (int c0 = 0; c0 < NCH; c0 += 256) {
        int c = c0 + t;
        int v = (c < NCH) ? cnt[c * NBK + b] : 0;
        sm[t] = v;
        __syncthreads();
        for (int o = 1; o < 256; o <<= 1) {
            int add = (t >= o) ? sm[t - o] : 0;
            __syncthreads();
            sm[t] += add;
            __syncthreads();
        }
        if (c < NCH) off[c * NBK + b] = carry + sm[t] - v;  // exclusive
        carry += sm[255];
        __syncthreads();
    }
    if (t == 0) tot[b] = carry;
}

// Pass B2: tiny single-block exclusive scan of bucket totals -> bbase.
__global__ __launch_bounds__(256) void k_off_b(
    const int* __restrict__ tot, int* __restrict__ bbase)
{
    __shared__ int sm[NBK];
    int b = threadIdx.x;
    int v0 = tot[b];
    sm[b] = v0;
    __syncthreads();
    for (int o = 1; o < NBK; o <<= 1) {
        int v = (b >= o) ? sm[b - o] : 0;
        __syncthreads();
        sm[b] += v;
        __syncthreads();
    }
    bbase[b] = sm[b] - v0;
    if (b == NBK - 1) bbase[NBK] = sm[b];
}

// Pass C: re-read chunk edges, rank via LDS cursors (init from bbase+off),
// write packed (s | (d&mask)<<17) into the chunk's exclusive slab ranges.
__global__ __launch_bounds__(256) void k_place(
    const int* __restrict__ ei, int E, int N, int shift,
    const int* __restrict__ off, const int* __restrict__ bbase,
    unsigned* __restrict__ bslab)
{
    __shared__ int cur[NBK];
    int c = blockIdx.x;
    cur[threadIdx.x] = bbase[threadIdx.x] + off[c * NBK + threadIdx.x];
    __syncthreads();
    int Etot = E + N;
    int base = c * CH;
    int lim = min(base + CH, Etot);
    int mask = (1 << shift) - 1;
    for (int e = base + threadIdx.x; e < lim; e += 256) {
        int s, d;
        if (e < E) { s = ei[e]; d = ei[E + e]; }
        else       { s = e - E; d = s; }
        int b = d >> shift;
        int pos = atomicAdd(&cur[b], 1);  // LDS atomic
        bslab[pos] = (unsigned)s | ((unsigned)(d & mask) << 17);
    }
}

// Pass D: block per bucket: LDS fine histogram + scan -> row_ptr, then place
// srcs into the bucket's csr_src window (L2-local). LDS atomics only.
__global__ __launch_bounds__(256) void k_csr2(
    const int* __restrict__ bbase, const unsigned* __restrict__ bslab,
    int shift, int* __restrict__ row_ptr, int* __restrict__ csr_src,
    int N, int Etot)
{
    __shared__ int sdeg[1024];
    __shared__ int scur[1024];
    __shared__ int ps[256];
    int b = blockIdx.x;
    int tid = threadIdx.x;
    int beg = bbase[b], end = bbase[b + 1];
    int nodes = 1 << shift;            // 512 (shift=9); LDS sized for <=1024
    int node0 = b << shift;
    for (int i = tid; i < nodes; i += 256) sdeg[i] = 0;
    __syncthreads();
    for (int i = beg + tid; i < end; i += 256)
        atomicAdd(&sdeg[bslab[i] >> 17], 1);
    __syncthreads();
    int per = (nodes + 255) / 256;
    int mybase = tid * per;
    int sum = 0;
    for (int j = 0; j < per; j++) sum += sdeg[mybase + j];
    ps[tid] = sum;
    __syncthreads();
    int v0 = ps[tid];
    for (int o = 1; o < 256; o <<= 1) {
        int v = (tid >= o) ? ps[tid - o] : 0;
        __syncthreads();
        ps[tid] += v;
        __syncthreads();
    }
    int run = ps[tid] - v0;
    for (int j = 0; j < per; j++) {
        int i = mybase + j;
        int dgi = sdeg[i];
        scur[i] = beg + run;
        int node = node0 + i;
        if (node < N) row_ptr[node] = beg + run;
        run += dgi;
    }
    if (b == 0 && tid == 0) row_ptr[N] = Etot;
    __syncthreads();
    for (int i = beg + tid; i < end; i += 256) {
        unsigned w = bslab[i];
        int pos = atomicAdd(&scur[w >> 17], 1);  // LDS atomic
        csr_src[pos] = (int)(w & 0x1FFFFu);
    }
}

// ===========================================================================
// xl1 = x @ W1 [N,64] -> packed bf16; as1 logits stored FP16 (src-gathered
// stream: 1.6 MB array -> L2-resident, halves its line traffic in k_agg1);
// ad1 stays f32 (dst-local, streamed). 4 THREADS PER NODE, 16 ch each.
// ===========================================================================
__global__ __launch_bounds__(256) void k_gemm1(
    const float* __restrict__ x, const float* __restrict__ W1,
    const float* __restrict__ a_src1, const float* __restrict__ a_dst1,
    unsigned* __restrict__ xl1b, __half* __restrict__ as1h,
    float* __restrict__ ad1, int N, int F)
{
    __shared__ float Ws[128 * 64];
    __shared__ float asrc[64];
    __shared__ float adst[64];
    for (int i = threadIdx.x; i < F * 64; i += 256) Ws[i] = W1[i];
    if (threadIdx.x < 64) {
        asrc[threadIdx.x] = a_src1[threadIdx.x];
        adst[threadIdx.x] = a_dst1[threadIdx.x];
    }
    __syncthreads();

    int n = blockIdx.x * 64 + (threadIdx.x >> 2);
    int q = threadIdx.x & 3;       // channel quarter: channels 16q..16q+15
    if (n >= N) return;
    int c0 = q * 16;

    float acc[16];
#pragma unroll
    for (int c = 0; c < 16; c++) acc[c] = 0.0f;

    const float4* xr4 = (const float4*)(x + (size_t)n * F);
    for (int k4 = 0; k4 < F / 4; k4++) {
        float4 xv = xr4[k4];
        const float* w0 = &Ws[(k4 * 4 + 0) * 64 + c0];
        const float* w1 = &Ws[(k4 * 4 + 1) * 64 + c0];
        const float* w2 = &Ws[(k4 * 4 + 2) * 64 + c0];
        const float* w3 = &Ws[(k4 * 4 + 3) * 64 + c0];
#pragma unroll
        for (int c = 0; c < 16; c++) {
            float a = acc[c];
            a = fmaf(xv.x, w0[c], a);
            a = fmaf(xv.y, w1[c], a);
            a = fmaf(xv.z, w2[c], a);
            a = fmaf(xv.w, w3[c], a);
            acc[c] = a;
        }
    }

    uint4 pk0, pk1;
    pk0.x = pack_bf16(acc[0], acc[1]);  pk0.y = pack_bf16(acc[2], acc[3]);
    pk0.z = pack_bf16(acc[4], acc[5]);  pk0.w = pack_bf16(acc[6], acc[7]);
    pk1.x = pack_bf16(acc[8], acc[9]);  pk1.y = pack_bf16(acc[10], acc[11]);
    pk1.z = pack_bf16(acc[12], acc[13]); pk1.w = pack_bf16(acc[14], acc[15]);
    uint4* xo = (uint4*)(xl1b + (size_t)n * 32 + q * 8);
    xo[0] = pk0;
    xo[1] = pk1;

#pragma unroll
    for (int hh = 0; hh < 2; hh++) {
        float s = 0.0f, t = 0.0f;
#pragma unroll
        for (int c = 0; c < 8; c++) {
            s = fmaf(acc[hh * 8 + c], asrc[c0 + hh * 8 + c], s);
            t = fmaf(acc[hh * 8 + c], adst[c0 + hh * 8 + c], t);
        }
        as1h[(size_t)n * 8 + 2 * q + hh] = __float2half(s);
        ad1[(size_t)n * 8 + 2 * q + hh] = t;
    }
}

// ===========================================================================
// Layer-1 aggregation (pull), 8-lanes-per-edge, unrolled x2; as1 read FP16.
// ===========================================================================
__global__ __launch_bounds__(256) void k_agg1(
    const int* __restrict__ row_ptr, const int* __restrict__ csr_src,
    const __half* __restrict__ as1h, const float* __restrict__ ad1,
    const unsigned* __restrict__ xl1b, const float* __restrict__ b1,
    float* __restrict__ h1, int N)
{
    int d = blockIdx.x * 4 + (threadIdx.x >> 6);
    int lane = threadIdx.x & 63;
    if (d >= N) return;
    int g = lane >> 3;   // edge group
    int l = lane & 7;    // head / channel octet

    int beg = row_ptr[d], end = row_ptr[d + 1];
    float adh = ad1[(size_t)d * 8 + l];

    float ax[8];
#pragma unroll
    for (int j = 0; j < 8; j++) ax[j] = 0.f;
    float den = 0.f;

    int i = beg + g;
    for (; i + 8 < end; i += 16) {
        int s0 = csr_src[i];
        int s1 = csr_src[i + 8];
        float al0 = __half2float(as1h[(size_t)s0 * 8 + l]) + adh;
        float al1 = __half2float(as1h[(size_t)s1 * 8 + l]) + adh;
        uint4 k0 = *(const uint4*)(xl1b + (size_t)s0 * 32 + l * 4);
        uint4 k1 = *(const uint4*)(xl1b + (size_t)s1 * 32 + l * 4);
        al0 = al0 > 0.f ? al0 : NEG_SLOPE * al0;
        al1 = al1 > 0.f ? al1 : NEG_SLOPE * al1;
        float e0 = __expf(al0);
        float e1 = __expf(al1);
        ax[0] = fmaf(e0, bf_lo(k0.x), ax[0]);
        ax[1] = fmaf(e0, bf_hi(k0.x), ax[1]);
        ax[2] = fmaf(e0, bf_lo(k0.y), ax[2]);
        ax[3] = fmaf(e0, bf_hi(k0.y), ax[3]);
        ax[4] = fmaf(e0, bf_lo(k0.z), ax[4]);
        ax[5] = fmaf(e0, bf_hi(k0.z), ax[5]);
        ax[6] = fmaf(e0, bf_lo(k0.w), ax[6]);
        ax[7] = fmaf(e0, bf_hi(k0.w), ax[7]);
        ax[0] = fmaf(e1, bf_lo(k1.x), ax[0]);
        ax[1] = fmaf(e1, bf_hi(k1.x), ax[1]);
        ax[2] = fmaf(e1, bf_lo(k1.y), ax[2]);
        ax[3] = fmaf(e1, bf_hi(k1.y), ax[3]);
        ax[4] = fmaf(e1, bf_lo(k1.z), ax[4]);
        ax[5] = fmaf(e1, bf_hi(k1.z), ax[5]);
        ax[6] = fmaf(e1, bf_lo(k1.w), ax[6]);
        ax[7] = fmaf(e1, bf_hi(k1.w), ax[7]);
        den += e0 + e1;
    }
    if (i < end) {
        int s0 = csr_src[i];
        float al0 = __half2float(as1h[(size_t)s0 * 8 + l]) + adh;
        uint4 k0 = *(const uint4*)(xl1b + (size_t)s0 * 32 + l * 4);
        al0 = al0 > 0.f ? al0 : NEG_SLOPE * al0;
        float e0 = __expf(al0);
        ax[0] = fmaf(e0, bf_lo(k0.x), ax[0]);
        ax[1] = fmaf(e0, bf_hi(k0.x), ax[1]);
        ax[2] = fmaf(e0, bf_lo(k0.y), ax[2]);
        ax[3] = fmaf(e0, bf_hi(k0.y), ax[3]);
        ax[4] = fmaf(e0, bf_lo(k0.z), ax[4]);
        ax[5] = fmaf(e0, bf_hi(k0.z), ax[5]);
        ax[6] = fmaf(e0, bf_lo(k0.w), ax[6]);
        ax[7] = fmaf(e0, bf_hi(k0.w), ax[7]);
        den += e0;
    }

#pragma unroll
    for (int m = 8; m < 64; m <<= 1) {
#pragma unroll
        for (int j = 0; j < 8; j++) ax[j] += __shfl_xor(ax[j], m);
        den += __shfl_xor(den, m);
    }

    if (g == 0) {
        float inv = 1.f / (den + GAT_EPS);
        const float4* bb = (const float4*)(b1 + l * 8);
        float4 b0 = bb[0], b1v = bb[1];
        float4 o0, o1;
        float v;
        v = ax[0] * inv + b0.x; o0.x = v > 0.f ? v : expm1f(v);
        v = ax[1] * inv + b0.y; o0.y = v > 0.f ? v : expm1f(v);
        v = ax[2] * inv + b0.z; o0.z = v > 0.f ? v : expm1f(v);
        v = ax[3] * inv + b0.w; o0.w = v > 0.f ? v : expm1f(v);
        v = ax[4] * inv + b1v.x; o1.x = v > 0.f ? v : expm1f(v);
        v = ax[5] * inv + b1v.y; o1.y = v > 0.f ? v : expm1f(v);
        v = ax[6] * inv + b1v.z; o1.z = v > 0.f ? v : expm1f(v);
        v = ax[7] * inv + b1v.w; o1.w = v > 0.f ? v : expm1f(v);
        float4* op = (float4*)(h1 + (size_t)d * 64 + l * 8);
        op[0] = o0;
        op[1] = o1;
    }
}

// ===========================================================================
// Layer-2 node transform: 2 THREADS PER NODE, 20 channels each.
// Compact bf16 rows, stride 20 uints (80 B).
// ===========================================================================
__global__ __launch_bounds__(256) void k_node2(
    const float* __restrict__ h1, const float* __restrict__ W2,
    const float* __restrict__ a_src2, const float* __restrict__ a_dst2,
    unsigned* __restrict__ xl2b, float* __restrict__ as2,
    float* __restrict__ ad2, int N)
{
    __shared__ float Ws[64 * 40];
    __shared__ float a2s[40];
    __shared__ float a2d[40];
    for (int i = threadIdx.x; i < 64 * 40; i += 256) Ws[i] = W2[i];
    if (threadIdx.x < 40) {
        a2s[threadIdx.x] = a_src2[threadIdx.x];
        a2d[threadIdx.x] = a_dst2[threadIdx.x];
    }
    __syncthreads();

    int n = blockIdx.x * 128 + (threadIdx.x >> 1);
    int q = threadIdx.x & 1;      // channel half: channels 20q..20q+19
    if (n >= N) return;
    int c0 = q * 20;

    float o[20];
#pragma unroll
    for (int j = 0; j < 20; j++) o[j] = 0.0f;

    const float4* hr4 = (const float4*)(h1 + (size_t)n * 64);
    for (int k4 = 0; k4 < 16; k4++) {
        float4 hv = hr4[k4];
        const float* w0 = &Ws[(k4 * 4 + 0) * 40 + c0];
        const float* w1 = &Ws[(k4 * 4 + 1) * 40 + c0];
        const float* w2 = &Ws[(k4 * 4 + 2) * 40 + c0];
        const float* w3 = &Ws[(k4 * 4 + 3) * 40 + c0];
#pragma unroll
        for (int j = 0; j < 20; j++) {
            float a = o[j];
            a = fmaf(hv.x, w0[j], a);
            a = fmaf(hv.y, w1[j], a);
            a = fmaf(hv.z, w2[j], a);
            a = fmaf(hv.w, w3[j], a);
            o[j] = a;
        }
    }

    float s = 0.0f, t = 0.0f;
#pragma unroll
    for (int j = 0; j < 20; j++) {
        s = fmaf(o[j], a2s[c0 + j], s);
        t = fmaf(o[j], a2d[c0 + j], t);
    }
    s += __shfl_xor(s, 1);
    t += __shfl_xor(t, 1);
    if (q == 0) { as2[n] = s; ad2[n] = t; }

    unsigned* xo = xl2b + (size_t)n * 20 + q * 10;
#pragma unroll
    for (int p = 0; p < 10; p++) xo[p] = pack_bf16(o[2 * p], o[2 * p + 1]);
}

// ===========================================================================
// Layer-2 aggregation (pull), 8 edges in flight, unrolled x2, l<5 active.
// ===========================================================================
__global__ __launch_bounds__(256) void k_agg2(
    const int* __restrict__ row_ptr, const int* __restrict__ csr_src,
    const float* __restrict__ as2, const float* __restrict__ ad2,
    const unsigned* __restrict__ xl2b, const float* __restrict__ b2,
    float* __restrict__ out, int N)
{
    int d = blockIdx.x * 4 + (threadIdx.x >> 6);
    int lane = threadIdx.x & 63;
    if (d >= N) return;
    int g = lane >> 3;
    int l = lane & 7;
    if (l >= 5) return;   // only 5 octets of 40 channels; reduction is l-local

    int beg = row_ptr[d], end = row_ptr[d + 1];
    float add = ad2[d];

    float ax[8];
#pragma unroll
    for (int j = 0; j < 8; j++) ax[j] = 0.f;
    float den = 0.f;

    int i = beg + g;
    for (; i + 8 < end; i += 16) {
        int s0 = csr_src[i];
        int s1 = csr_src[i + 8];
        float al0 = as2[s0] + add;
        float al1 = as2[s1] + add;
        uint4 k0 = *(const uint4*)(xl2b + (size_t)s0 * 20 + l * 4);
        uint4 k1 = *(const uint4*)(xl2b + (size_t)s1 * 20 + l * 4);
        al0 = al0 > 0.f ? al0 : NEG_SLOPE * al0;
        al1 = al1 > 0.f ? al1 : NEG_SLOPE * al1;
        float e0 = __expf(al0);
        float e1 = __expf(al1);
        ax[0] = fmaf(e0, bf_lo(k0.x), ax[0]);
        ax[1] = fmaf(e0, bf_hi(k0.x), ax[1]);
        ax[2] = fmaf(e0, bf_lo(k0.y), ax[2]);
        ax[3] = fmaf(e0, bf_hi(k0.y), ax[3]);
        ax[4] = fmaf(e0, bf_lo(k0.z), ax[4]);
        ax[5] = fmaf(e0, bf_hi(k0.z), ax[5]);
        ax[6] = fmaf(e0, bf_lo(k0.w), ax[6]);
        ax[7] = fmaf(e0, bf_hi(k0.w), ax[7]);
        ax[0] = fmaf(e1, bf_lo(k1.x), ax[0]);
        ax[1] = fmaf(e1, bf_hi(k1.x), ax[1]);
        ax[2] = fmaf(e1, bf_lo(k1.y), ax[2]);
        ax[3] = fmaf(e1, bf_hi(k1.y), ax[3]);
        ax[4] = fmaf(e1, bf_lo(k1.z), ax[4]);
        ax[5] = fmaf(e1, bf_hi(k1.z), ax[5]);
        ax[6] = fmaf(e1, bf_lo(k1.w), ax[6]);
        ax[7] = fmaf(e1, bf_hi(k1.w), ax[7]);
        den += e0 + e1;
    }
    if (i < end) {
        int s0 = csr_src[i];
        float al0 = as2[s0] + add;
        uint4 k0 = *(const uint4*)(xl2b + (size_t)s0 * 20 + l * 4);
        al0 = al0 > 0.f ? al0 : NEG_SLOPE * al0;
        float e0 = __expf(al0);
        ax[0] = fmaf(e0, bf_lo(k0.x), ax[0]);
        ax[1] = fmaf(e0, bf_hi(k0.x), ax[1]);
        ax[2] = fmaf(e0, bf_lo(k0.y), ax[2]);
        ax[3] = fmaf(e0, bf_hi(k0.y), ax[3]);
        ax[4] = fmaf(e0, bf_lo(k0.z), ax[4]);
        ax[5] = fmaf(e0, bf_hi(k0.z), ax[5]);
        ax[6] = fmaf(e0, bf_lo(k0.w), ax[6]);
        ax[7] = fmaf(e0, bf_hi(k0.w), ax[7]);
        den += e0;
    }

#pragma unroll
    for (int m = 8; m < 64; m <<= 1) {
#pragma unroll
        for (int j = 0; j < 8; j++) ax[j] += __shfl_xor(ax[j], m);
        den += __shfl_xor(den, m);
    }

    if (g == 0) {
        float inv = 1.f / (den + GAT_EPS);
        float* op = out + (size_t)d * 40 + l * 8;
        const float* bb = b2 + l * 8;
#pragma unroll
        for (int j = 0; j < 8; j++) op[j] = ax[j] * inv + bb[j];
    }
}

extern "C" void kernel_launch(void* const* d_in, const int* in_sizes, int n_in,
                              void* d_out, int out_size, void* d_ws, size_t ws_size,
                              hipStream_t stream) {
    const float* x      = (const float*)d_in[0];
    const int*   ei     = (const int*)d_in[1];     // int32 on device
    const float* W1     = (const float*)d_in[2];
    const float* a_src1 = (const float*)d_in[3];
    const float* a_dst1 = (const float*)d_in[4];
    const float* b1     = (const float*)d_in[5];
    const float* W2     = (const float*)d_in[6];
    const float* a_src2 = (const float*)d_in[7];
    const float* a_dst2 = (const float*)d_in[8];
    const float* b2     = (const float*)d_in[9];

    int F = in_sizes[2] / 64;      // 128
    int N = in_sizes[0] / F;       // 100000
    int E = in_sizes[1] / 2;       // 1600000
    int Etot = E + N;
    int NCH = (Etot + CH - 1) / CH;  // 208 chunks
    int shift = 9;                   // 512 nodes/bucket; N<131072 -> <=196 buckets
    while (((N - 1) >> shift) >= NBK) shift++;  // safety (LDS supports shift<=10)

    // Workspace (4-byte words). Peak ~59 MB.
    unsigned* xl1b    = (unsigned*)d_ws;                   // N*32
    float*    h1      = (float*)(xl1b + (size_t)N * 32);   // N*64
    __half*   as1h    = (__half*)(h1 + (size_t)N * 64);    // N*8 halfs (N*4 words)
    float*    ad1     = (float*)(as1h + (size_t)N * 8);    // N*8
    int*      row_ptr = (int*)(ad1 + (size_t)N * 8);       // N+1
    int*      csr_src = row_ptr + (N + 1);                 // Etot
    int*      cnt     = csr_src + Etot;                    // NCH*NBK
    int*      off     = cnt + (size_t)NCH * NBK;           // NCH*NBK
    int*      tot     = off + (size_t)NCH * NBK;           // NBK
    int*      bbase   = tot + NBK;                         // NBK+1
    unsigned* bslab   = (unsigned*)(bbase + NBK + 1);      // Etot
    // Aliases (live only after k_agg1; originals dead by then):
    unsigned* xl2b    = xl1b;                              // N*20 compact rows
    float*    as2     = (float*)as1h;                      // N floats (fits in N*4 words)
    float*    ad2     = ad1;                               // N

    // ---- CSR build: deterministic counting sort, zero global atomics ----
    k_cnt  <<<NCH, 256, 0, stream>>>(ei, E, N, shift, cnt);
    k_off_a<<<NBK, 256, 0, stream>>>(cnt, off, tot, NCH);
    k_off_b<<<1, 256, 0, stream>>>(tot, bbase);
    k_place<<<NCH, 256, 0, stream>>>(ei, E, N, shift, off, bbase, bslab);
    k_csr2 <<<NBK, 256, 0, stream>>>(bbase, bslab, shift,
                                     row_ptr, csr_src, N, Etot);

    // ---- Layer 1 ----
    k_gemm1<<<(N + 63) / 64, 256, 0, stream>>>(x, W1, a_src1, a_dst1,
                                               xl1b, as1h, ad1, N, F);
    k_agg1 <<<(N + 3) / 4, 256, 0, stream>>>(row_ptr, csr_src, as1h, ad1,
                                             xl1b, b1, h1, N);

    // ---- Layer 2 ----
    k_node2<<<(N + 127) / 128, 256, 0, stream>>>(h1, W2, a_src2, a_dst2,
                                                 xl2b, as2, ad2, N);
    k_agg2 <<<(N + 3) / 4, 256, 0, stream>>>(row_ptr, csr_src, as2, ad2,
                                             xl2b, b2, (float*)d_out, N);
}